// Round 16
// baseline (171.536 us; speedup 1.0000x reference)
//
#include <hip/hip_runtime.h>
#include <hip/hip_bf16.h>

typedef __attribute__((ext_vector_type(8))) short bf16x8;
typedef __attribute__((ext_vector_type(4))) float f32x4;

#define N_TOKENS 16384
#define DIM 4096
#define KQ 1024            // K floats per wave (one quarter)
#define CH 64              // chunk floats staged per step
#define NCH (KQ / CH)      // 16 chunks
#define N_EXP 64

// d_out layout (all float32):
//   [0, 32768)              topk_experts as float  [token][2]
//   [32768, 65536)          combine_weight         [token][2]
//   [65536, 65536+1048576)  scores                 [token][64]
//   [1114112]               load_balance_loss
//   [1114113]               z_loss
#define OFF_W   (N_TOKENS * 2)
#define OFF_S   (N_TOKENS * 4)
#define OFF_LBL (N_TOKENS * 4 + N_TOKENS * N_EXP)
#define OFF_Z   (OFF_LBL + 1)

// ws layout (floats): [0..63] me, [64..127] ce, [128] z,
// [512..) w_hi ushort[64*4096], w_lo ushort[64*4096], then 4 partial-logit planes
#define WS_WHI_F 512
#define WS_WLO_F (WS_WHI_F + (N_EXP * DIM) / 2)
#define WS_PART_F (WS_WLO_F + (N_EXP * DIM) / 2)

typedef const __attribute__((address_space(1))) void GV;
typedef __attribute__((address_space(3))) void LV;

// ---- cheap truncation split: f = hi + r exactly; lo = trunc(r). ~3 VALU/elem.
__device__ __forceinline__ unsigned int pkhi(float a, float b) {
  return __builtin_amdgcn_perm(__float_as_uint(b), __float_as_uint(a), 0x07060302u);
}
__device__ __forceinline__ float resid(float f) {
  return f - __uint_as_float(__float_as_uint(f) & 0xFFFF0000u);
}
__device__ __forceinline__ void tsplit8(const f32x4 p0, const f32x4 p1,
                                        bf16x8& hi, bf16x8& lo) {
  uint4 H = make_uint4(pkhi(p0[0], p0[1]), pkhi(p0[2], p0[3]),
                       pkhi(p1[0], p1[1]), pkhi(p1[2], p1[3]));
  float r0 = resid(p0[0]), r1 = resid(p0[1]), r2 = resid(p0[2]), r3 = resid(p0[3]);
  float r4 = resid(p1[0]), r5 = resid(p1[1]), r6 = resid(p1[2]), r7 = resid(p1[3]);
  uint4 L = make_uint4(pkhi(r0, r1), pkhi(r2, r3), pkhi(r4, r5), pkhi(r6, r7));
  hi = __builtin_bit_cast(bf16x8, H);
  lo = __builtin_bit_cast(bf16x8, L);
}

// pre-pass: w fp32 -> bf16 hi/lo planes (RNE)
__global__ __launch_bounds__(256) void split_w_kernel(
    const float* __restrict__ w,
    unsigned short* __restrict__ whi, unsigned short* __restrict__ wlo)
{
  const int i = blockIdx.x * 256 + threadIdx.x;
  float f = w[i];
  unsigned short h = __builtin_bit_cast(unsigned short, __float2bfloat16(f));
  float hf = __uint_as_float(((unsigned)h) << 16);
  unsigned short l = __builtin_bit_cast(unsigned short, __float2bfloat16(f - hf));
  whi[i] = h;
  wlo[i] = l;
}

// ---- barrier-free GEMM: wave owns 16 tokens x 64 experts x one K-quarter ----
// block = 512 threads = 8 waves = 2 token-groups x 4 K-quarters; grid = 512
__global__ __launch_bounds__(512, 4) void router_kernel(
    const float* __restrict__ x,
    const unsigned short* __restrict__ whi, const unsigned short* __restrict__ wlo,
    float* __restrict__ part)
{
  // 8 waves x 2 bufs x [16 rows x 64 floats] = 64 KB, wave-private regions.
  // LDS[row][u] = x[row][u ^ (row&7)]  (16B-unit source swizzle, involution)
  __shared__ __align__(16) float smem[8 * 2 * 16 * CH];

  const int tid  = threadIdx.x;
  const int lane = tid & 63;
  const int wv   = __builtin_amdgcn_readfirstlane(tid >> 6);  // 0..7
  const int g    = wv & 1;     // token group (16 tokens)
  const int kq   = wv >> 1;    // K quarter 0..3
  const int half = lane >> 4;  // 0..3
  const int r15  = lane & 15;
  const int tok0 = blockIdx.x * 32 + g * 16;

  float* const base = smem + wv * (2 * 16 * CH);  // wave-private, wave-uniform

  // staging: gll instr i covers rows 4i..4i+3 (1 KB LDS contiguous);
  // lane -> row = 4i + (lane>>4), unit u = lane&15, source unit = u ^ (row&7)
  const int lrow = lane >> 4;
  const int u    = lane & 15;
  const float* gsrc[4];
#pragma unroll
  for (int i = 0; i < 4; ++i) {
    const int row = 4 * i + lrow;
    gsrc[i] = x + (size_t)(tok0 + row) * DIM + kq * KQ + ((u ^ (row & 7)) << 2);
  }

#define STAGE(bufsel, it_) do {                                                   \
    float* dB_ = base + (bufsel) * (16 * CH);                                     \
    __builtin_amdgcn_global_load_lds((GV*)(gsrc[0] + (size_t)(it_) * CH),         \
                                     (LV*)(dB_ + 0 * 256), 16, 0, 0);             \
    __builtin_amdgcn_global_load_lds((GV*)(gsrc[1] + (size_t)(it_) * CH),         \
                                     (LV*)(dB_ + 1 * 256), 16, 0, 0);             \
    __builtin_amdgcn_global_load_lds((GV*)(gsrc[2] + (size_t)(it_) * CH),         \
                                     (LV*)(dB_ + 2 * 256), 16, 0, 0);             \
    __builtin_amdgcn_global_load_lds((GV*)(gsrc[3] + (size_t)(it_) * CH),         \
                                     (LV*)(dB_ + 3 * 256), 16, 0, 0);             \
  } while (0)

  // w fragments: expert = n*16 + r15, k = kq*KQ + it*CH + ks*32 + half*8 + j
  const unsigned short* wh0 = whi + (size_t)r15 * DIM + kq * KQ + half * 8;
  const unsigned short* wl0 = wlo + (size_t)r15 * DIM + kq * KQ + half * 8;

  f32x4 acc[4];
#pragma unroll
  for (int n = 0; n < 4; ++n) acc[n] = (f32x4){0.f, 0.f, 0.f, 0.f};

  // prologue: stage chunks 0,1
  STAGE(0, 0);
  STAGE(1, 1);

  for (int it = 0; it < NCH; ++it) {
    const float* bufp = base + (it & 1) * (16 * CH);
    const int g8 = r15 & 7;
    const float* rp = bufp + r15 * CH;

    // --- k32 #0: w loads (8), then wait stage(it) done: vmcnt(12) leaves
    //     stage(it+1)(4) + these 8 in flight ---
    bf16x8 bh[4], bl[4];
#pragma unroll
    for (int n = 0; n < 4; ++n) {
      const size_t o = (size_t)it * CH + (size_t)n * 16 * DIM;
      bh[n] = *(const bf16x8*)(wh0 + o);
      bl[n] = *(const bf16x8*)(wl0 + o);
    }
    asm volatile("s_waitcnt vmcnt(12)" ::: "memory");
    {
      const int b0 = (half * 2) ^ g8, b1 = (half * 2 + 1) ^ g8;
      f32x4 p0 = *(const f32x4*)(rp + (b0 << 2));
      f32x4 p1 = *(const f32x4*)(rp + (b1 << 2));
      bf16x8 ah, al;
      tsplit8(p0, p1, ah, al);
#pragma unroll
      for (int n = 0; n < 4; ++n) {
        acc[n] = __builtin_amdgcn_mfma_f32_16x16x32_bf16(ah, bh[n], acc[n], 0, 0, 0);
        acc[n] = __builtin_amdgcn_mfma_f32_16x16x32_bf16(al, bh[n], acc[n], 0, 0, 0);
        acc[n] = __builtin_amdgcn_mfma_f32_16x16x32_bf16(ah, bl[n], acc[n], 0, 0, 0);
      }
    }

    // --- k32 #1 ---
#pragma unroll
    for (int n = 0; n < 4; ++n) {
      const size_t o = (size_t)it * CH + 32 + (size_t)n * 16 * DIM;
      bh[n] = *(const bf16x8*)(wh0 + o);
      bl[n] = *(const bf16x8*)(wl0 + o);
    }
    {
      const int b0 = (8 + half * 2) ^ g8, b1 = (8 + half * 2 + 1) ^ g8;
      f32x4 p0 = *(const f32x4*)(rp + (b0 << 2));
      f32x4 p1 = *(const f32x4*)(rp + (b1 << 2));
      bf16x8 ah, al;
      tsplit8(p0, p1, ah, al);
#pragma unroll
      for (int n = 0; n < 4; ++n) {
        acc[n] = __builtin_amdgcn_mfma_f32_16x16x32_bf16(ah, bh[n], acc[n], 0, 0, 0);
        acc[n] = __builtin_amdgcn_mfma_f32_16x16x32_bf16(al, bh[n], acc[n], 0, 0, 0);
        acc[n] = __builtin_amdgcn_mfma_f32_16x16x32_bf16(ah, bl[n], acc[n], 0, 0, 0);
      }
    }

    // this wave's reads of buf(it&1) are complete before restaging into it
    asm volatile("s_waitcnt lgkmcnt(0)" ::: "memory");
    STAGE(it & 1, (it + 2 < NCH) ? it + 2 : NCH - 1);
  }

  // store partial logits: C frag: token = half*4 + r, expert = n*16 + r15
#pragma unroll
  for (int n = 0; n < 4; ++n) {
#pragma unroll
    for (int r = 0; r < 4; ++r) {
      part[((size_t)kq * N_TOKENS + tok0 + half * 4 + r) * 64 + n * 16 + r15] = acc[n][r];
    }
  }
#undef STAGE
}

// ---- epilogue: combine 4 partials + softmax + top-2 + losses + scores ----
__global__ __launch_bounds__(256) void epilogue_kernel(
    const float* __restrict__ part, float* __restrict__ out, float* __restrict__ ws)
{
  __shared__ float lds[64 * 65];
  const int tid  = threadIdx.x;
  const int lane = tid & 63;
  const int wv   = tid >> 6;
  const int tok0 = blockIdx.x * 64;

  for (int i = tid; i < 64 * 64; i += 256) {
    const int t = i >> 6, e = i & 63;
    const size_t idx = (size_t)(tok0 + t) * 64 + e;
    lds[t * 65 + e] = part[idx]
                    + part[(size_t)N_TOKENS * 64 + idx]
                    + part[(size_t)2 * N_TOKENS * 64 + idx]
                    + part[(size_t)3 * N_TOKENS * 64 + idx];
  }
  __syncthreads();

  if (wv == 0) {
    const int token = tok0 + lane;  // 64 lanes, 64 tokens
    float v[64];
#pragma unroll
    for (int e = 0; e < 64; ++e) v[e] = lds[lane * 65 + e];
    float m = v[0];
#pragma unroll
    for (int e = 1; e < 64; ++e) m = fmaxf(m, v[e]);
    float sum = 0.f;
#pragma unroll
    for (int e = 0; e < 64; ++e) { v[e] = expf(v[e] - m); sum += v[e]; }
    const float inv = 1.0f / sum;
    float m1 = -1.f, m2 = -1.f;
    int   i1 = 0,    i2 = 0;
#pragma unroll
    for (int e = 0; e < 64; ++e) {
      float sc = v[e] * inv;
      lds[lane * 65 + e] = sc;
      if (sc > m1)      { m2 = m1; i2 = i1; m1 = sc; i1 = e; }
      else if (sc > m2) { m2 = sc; i2 = e; }
    }
    out[2 * token]             = (float)i1;
    out[2 * token + 1]         = (float)i2;
    out[OFF_W + 2 * token]     = m1;
    out[OFF_W + 2 * token + 1] = m2;

    float lse = m + logf(sum);
    float z = lse * lse;
#pragma unroll
    for (int off = 32; off > 0; off >>= 1) z += __shfl_down(z, off);
    if (lane == 0) atomicAdd(ws + 128, z);
  }
  __syncthreads();

  float* outS = out + OFF_S + (size_t)blockIdx.x * 64 * 64;
  for (int i = tid; i < 64 * 64; i += 256) {
    outS[i] = lds[(i >> 6) * 65 + (i & 63)];
  }

  if (wv == 0) {
    float sm = 0.f, cn = 0.f;
#pragma unroll
    for (int t = 0; t < 64; ++t) {
      float sc = lds[t * 65 + lane];
      sm += sc;
      cn += (sc > 0.f) ? 1.f : 0.f;
    }
    atomicAdd(ws + lane, sm);
    atomicAdd(ws + 64 + lane, cn);
  }
}

__global__ void finalize_kernel(const float* __restrict__ ws, float* __restrict__ out) {
  const int l = threadIdx.x;  // 64 threads
  const float invT = 1.0f / (float)N_TOKENS;
  float me = ws[l] * invT;
  float ce = ws[64 + l] * invT;
  float p = me * ce;
#pragma unroll
  for (int off = 32; off > 0; off >>= 1) p += __shfl_down(p, off);
  if (l == 0) {
    out[OFF_LBL] = p * (float)N_EXP;
    out[OFF_Z]   = ws[128] * invT;
  }
}

extern "C" void kernel_launch(void* const* d_in, const int* in_sizes, int n_in,
                              void* d_out, int out_size, void* d_ws, size_t ws_size,
                              hipStream_t stream) {
  const float* x = (const float*)d_in[0];
  const float* w = (const float*)d_in[1];
  float* out = (float*)d_out;
  float* ws  = (float*)d_ws;
  unsigned short* whi = (unsigned short*)(ws + WS_WHI_F);
  unsigned short* wlo = (unsigned short*)(ws + WS_WLO_F);
  float* part = ws + WS_PART_F;

  (void)hipMemsetAsync(d_ws, 0, 129 * sizeof(float), stream);
  split_w_kernel<<<(N_EXP * DIM) / 256, 256, 0, stream>>>(w, whi, wlo);
  router_kernel<<<N_TOKENS / 32, 512, 0, stream>>>(x, whi, wlo, part);
  epilogue_kernel<<<N_TOKENS / 64, 256, 0, stream>>>(part, out, ws);
  finalize_kernel<<<1, 64, 0, stream>>>(ws, out);
}

// Round 17
// 126.091 us; speedup vs baseline: 1.3604x; 1.3604x over previous
//
#include <hip/hip_runtime.h>
#include <hip/hip_bf16.h>

typedef __attribute__((ext_vector_type(8))) short bf16x8;
typedef __attribute__((ext_vector_type(4))) float f32x4;

#define N_TOKENS 16384
#define DIM 4096
#define TOKB 32            // tokens per block
#define KHALF 2048         // K per block (half of DIM)
#define BK 64              // K floats per staged chunk
#define NCH (KHALF / BK)   // 32 chunks
#define BUF_F (TOKB * BK)  // 2048 floats = 8 KB per buffer, 4 buffers
#define N_EXP 64

// d_out layout (all float32):
//   [0, 32768)              topk_experts as float  [token][2]
//   [32768, 65536)          combine_weight         [token][2]
//   [65536, 65536+1048576)  scores                 [token][64]
//   [1114112]               load_balance_loss
//   [1114113]               z_loss
#define OFF_W   (N_TOKENS * 2)
#define OFF_S   (N_TOKENS * 4)
#define OFF_LBL (N_TOKENS * 4 + N_TOKENS * N_EXP)
#define OFF_Z   (OFF_LBL + 1)

// ws layout (floats): [0..63] me, [64..127] ce, [128] z,
// [512..) w_hi ushort[64*4096], w_lo ushort[64*4096], then 4 partial-logit planes
#define WS_WHI_F 512
#define WS_WLO_F (WS_WHI_F + (N_EXP * DIM) / 2)
#define WS_PART_F (WS_WLO_F + (N_EXP * DIM) / 2)

typedef const __attribute__((address_space(1))) void GV;
typedef __attribute__((address_space(3))) void LV;

// ---- cheap truncation split: f = hi + r exactly; lo = trunc(r). ~3 VALU/elem.
__device__ __forceinline__ unsigned int pkhi(float a, float b) {
  return __builtin_amdgcn_perm(__float_as_uint(b), __float_as_uint(a), 0x07060302u);
}
__device__ __forceinline__ float resid(float f) {
  return f - __uint_as_float(__float_as_uint(f) & 0xFFFF0000u);
}
__device__ __forceinline__ void tsplit8(const f32x4 p0, const f32x4 p1,
                                        bf16x8& hi, bf16x8& lo) {
  uint4 H = make_uint4(pkhi(p0[0], p0[1]), pkhi(p0[2], p0[3]),
                       pkhi(p1[0], p1[1]), pkhi(p1[2], p1[3]));
  float r0 = resid(p0[0]), r1 = resid(p0[1]), r2 = resid(p0[2]), r3 = resid(p0[3]);
  float r4 = resid(p1[0]), r5 = resid(p1[1]), r6 = resid(p1[2]), r7 = resid(p1[3]);
  uint4 L = make_uint4(pkhi(r0, r1), pkhi(r2, r3), pkhi(r4, r5), pkhi(r6, r7));
  hi = __builtin_bit_cast(bf16x8, H);
  lo = __builtin_bit_cast(bf16x8, L);
}

// pre-pass: w fp32 -> bf16 hi/lo planes (RNE)
__global__ __launch_bounds__(256) void split_w_kernel(
    const float* __restrict__ w,
    unsigned short* __restrict__ whi, unsigned short* __restrict__ wlo)
{
  const int i = blockIdx.x * 256 + threadIdx.x;
  float f = w[i];
  unsigned short h = __builtin_bit_cast(unsigned short, __float2bfloat16(f));
  float hf = __uint_as_float(((unsigned)h) << 16);
  unsigned short l = __builtin_bit_cast(unsigned short, __float2bfloat16(f - hf));
  whi[i] = h;
  wlo[i] = l;
}

// ---- GEMM: block = 32 tokens x 64 experts x one K-half; 8 waves = 4 q x 2 kq ----
__global__ __launch_bounds__(512, 8) void router_kernel(
    const float* __restrict__ x,
    const unsigned short* __restrict__ whi, const unsigned short* __restrict__ wlo,
    float* __restrict__ part)
{
  // 4 fp32 x-chunk buffers [32][64] (8 KB each, 32 KB total).
  // LDS[row][u] = x[row][u ^ (row&7)]  (16B-unit source swizzle, involution)
  __shared__ __align__(16) float smem[4 * BUF_F];

  const int tid  = threadIdx.x;
  const int lane = tid & 63;
  const int wv   = __builtin_amdgcn_readfirstlane(tid >> 6);  // 0..7
  const int q    = wv & 3;     // expert group: 16 experts
  const int kq   = wv >> 2;    // k 32-slice within chunk: 0 or 1
  const int half = lane >> 4;  // 0..3
  const int r15  = lane & 15;
  const int g8   = r15 & 7;

  const int bid  = blockIdx.x;
  const int kh   = bid & 1;          // K half
  const int tok0 = (bid >> 1) * TOKB;

  // staging: one gll per wave covers rows wv*4 .. wv*4+3 (4 x 256 B = 1 KB)
  const int row = wv * 4 + (lane >> 4);
  const int u   = lane & 15;
  const float* gsrc = x + (size_t)(tok0 + row) * DIM + kh * KHALF + ((u ^ (row & 7)) << 2);
  float* const ldst = smem + wv * 4 * BK;  // wave-uniform

#define STAGE(bufsel, it_) \
  __builtin_amdgcn_global_load_lds((GV*)(gsrc + (size_t)(it_) * BK), \
                                   (LV*)(ldst + (bufsel) * BUF_F), 16, 0, 0)

  // w fragment base: expert = q*16 + r15, k = kh*KHALF + it*BK + kq*32 + half*8
  const unsigned short* wbh = whi + (size_t)(q * 16 + r15) * DIM + kh * KHALF + kq * 32 + half * 8;
  const unsigned short* wbl = wlo + (size_t)(q * 16 + r15) * DIM + kh * KHALF + kq * 32 + half * 8;

  f32x4 acc[2];
  acc[0] = (f32x4){0.f, 0.f, 0.f, 0.f};
  acc[1] = (f32x4){0.f, 0.f, 0.f, 0.f};

  // prologue: stage chunks 0,1,2; preload w(0) into set A
  STAGE(0, 0);
  STAGE(1, 1);
  STAGE(2, 2);
  bf16x8 whA = *(const bf16x8*)(wbh);
  bf16x8 wlA = *(const bf16x8*)(wbl);

#define COMPUTE(it_, WH, WL) do {                                              \
    const float* bufp = smem + ((it_) & 3) * BUF_F;                            \
    _Pragma("unroll")                                                          \
    for (int tt = 0; tt < 2; ++tt) {                                           \
      const float* rp = bufp + (tt * 16 + r15) * BK;                           \
      const int u0 = kq * 8 + ((half * 2)     ^ g8);                           \
      const int u1 = kq * 8 + ((half * 2 + 1) ^ g8);                           \
      f32x4 p0 = *(const f32x4*)(rp + (u0 << 2));                              \
      f32x4 p1 = *(const f32x4*)(rp + (u1 << 2));                              \
      bf16x8 ah, al;                                                           \
      tsplit8(p0, p1, ah, al);                                                 \
      acc[tt] = __builtin_amdgcn_mfma_f32_16x16x32_bf16(ah, WH, acc[tt], 0, 0, 0); \
      acc[tt] = __builtin_amdgcn_mfma_f32_16x16x32_bf16(al, WH, acc[tt], 0, 0, 0); \
      acc[tt] = __builtin_amdgcn_mfma_f32_16x16x32_bf16(ah, WL, acc[tt], 0, 0, 0); \
    }                                                                          \
  } while (0)

  for (int s = 0; s < NCH / 2; ++s) {
    const int it0 = 2 * s, it1 = 2 * s + 1;

    // even chunk: load w(it1) into set B, stage it0+3, wait, compute it0 with set A
    {
      const size_t ko = (size_t)it1 * BK;
      bf16x8 whB = *(const bf16x8*)(wbh + ko);
      bf16x8 wlB = *(const bf16x8*)(wbl + ko);
      STAGE((it0 + 3) & 3, (it0 + 3 < NCH) ? it0 + 3 : NCH - 1);
      asm volatile("s_waitcnt vmcnt(6)" ::: "memory");
      __builtin_amdgcn_s_barrier();
      COMPUTE(it0, whA, wlA);

      // odd chunk: load w(it0+2) into set A, stage it1+3, wait, compute it1 with set B
      const size_t ko2 = (size_t)((it0 + 2 < NCH) ? it0 + 2 : NCH - 1) * BK;
      whA = *(const bf16x8*)(wbh + ko2);
      wlA = *(const bf16x8*)(wbl + ko2);
      STAGE((it1 + 3) & 3, (it1 + 3 < NCH) ? it1 + 3 : NCH - 1);
      asm volatile("s_waitcnt vmcnt(6)" ::: "memory");
      __builtin_amdgcn_s_barrier();
      COMPUTE(it1, whB, wlB);
    }
  }

  // store partial logits: plane p = kh*2 + kq
  // C frag: token = tok0 + tt*16 + half*4 + r, expert = q*16 + r15
  const int p = (kh << 1) | kq;
#pragma unroll
  for (int tt = 0; tt < 2; ++tt) {
#pragma unroll
    for (int r = 0; r < 4; ++r) {
      part[((size_t)p * N_TOKENS + tok0 + tt * 16 + half * 4 + r) * 64 + q * 16 + r15] =
          acc[tt][r];
    }
  }
#undef STAGE
#undef COMPUTE
}

// ---- epilogue: combine 4 partials + softmax + top-2 + losses + scores ----
__global__ __launch_bounds__(256) void epilogue_kernel(
    const float* __restrict__ part, float* __restrict__ out, float* __restrict__ ws)
{
  __shared__ float lds[64 * 65];
  const int tid  = threadIdx.x;
  const int lane = tid & 63;
  const int wv   = tid >> 6;
  const int tok0 = blockIdx.x * 64;

  for (int i = tid; i < 64 * 64; i += 256) {
    const int t = i >> 6, e = i & 63;
    const size_t idx = (size_t)(tok0 + t) * 64 + e;
    lds[t * 65 + e] = part[idx]
                    + part[(size_t)N_TOKENS * 64 + idx]
                    + part[(size_t)2 * N_TOKENS * 64 + idx]
                    + part[(size_t)3 * N_TOKENS * 64 + idx];
  }
  __syncthreads();

  if (wv == 0) {
    const int token = tok0 + lane;  // 64 lanes, 64 tokens
    float v[64];
#pragma unroll
    for (int e = 0; e < 64; ++e) v[e] = lds[lane * 65 + e];
    float m = v[0];
#pragma unroll
    for (int e = 1; e < 64; ++e) m = fmaxf(m, v[e]);
    float sum = 0.f;
#pragma unroll
    for (int e = 0; e < 64; ++e) { v[e] = expf(v[e] - m); sum += v[e]; }
    const float inv = 1.0f / sum;
    float m1 = -1.f, m2 = -1.f;
    int   i1 = 0,    i2 = 0;
#pragma unroll
    for (int e = 0; e < 64; ++e) {
      float sc = v[e] * inv;
      lds[lane * 65 + e] = sc;
      if (sc > m1)      { m2 = m1; i2 = i1; m1 = sc; i1 = e; }
      else if (sc > m2) { m2 = sc; i2 = e; }
    }
    out[2 * token]             = (float)i1;
    out[2 * token + 1]         = (float)i2;
    out[OFF_W + 2 * token]     = m1;
    out[OFF_W + 2 * token + 1] = m2;

    float lse = m + logf(sum);
    float z = lse * lse;
#pragma unroll
    for (int off = 32; off > 0; off >>= 1) z += __shfl_down(z, off);
    if (lane == 0) atomicAdd(ws + 128, z);
  }
  __syncthreads();

  float* outS = out + OFF_S + (size_t)blockIdx.x * 64 * 64;
  for (int i = tid; i < 64 * 64; i += 256) {
    outS[i] = lds[(i >> 6) * 65 + (i & 63)];
  }

  if (wv == 0) {
    float sm = 0.f, cn = 0.f;
#pragma unroll
    for (int t = 0; t < 64; ++t) {
      float sc = lds[t * 65 + lane];
      sm += sc;
      cn += (sc > 0.f) ? 1.f : 0.f;
    }
    atomicAdd(ws + lane, sm);
    atomicAdd(ws + 64 + lane, cn);
  }
}

__global__ void finalize_kernel(const float* __restrict__ ws, float* __restrict__ out) {
  const int l = threadIdx.x;  // 64 threads
  const float invT = 1.0f / (float)N_TOKENS;
  float me = ws[l] * invT;
  float ce = ws[64 + l] * invT;
  float p = me * ce;
#pragma unroll
  for (int off = 32; off > 0; off >>= 1) p += __shfl_down(p, off);
  if (l == 0) {
    out[OFF_LBL] = p * (float)N_EXP;
    out[OFF_Z]   = ws[128] * invT;
  }
}

extern "C" void kernel_launch(void* const* d_in, const int* in_sizes, int n_in,
                              void* d_out, int out_size, void* d_ws, size_t ws_size,
                              hipStream_t stream) {
  const float* x = (const float*)d_in[0];
  const float* w = (const float*)d_in[1];
  float* out = (float*)d_out;
  float* ws  = (float*)d_ws;
  unsigned short* whi = (unsigned short*)(ws + WS_WHI_F);
  unsigned short* wlo = (unsigned short*)(ws + WS_WLO_F);
  float* part = ws + WS_PART_F;

  (void)hipMemsetAsync(d_ws, 0, 129 * sizeof(float), stream);
  split_w_kernel<<<(N_EXP * DIM) / 256, 256, 0, stream>>>(w, whi, wlo);
  router_kernel<<<(N_TOKENS / TOKB) * 2, 512, 0, stream>>>(x, whi, wlo, part);
  epilogue_kernel<<<N_TOKENS / 64, 256, 0, stream>>>(part, out, ws);
  finalize_kernel<<<1, 64, 0, stream>>>(ws, out);
}

// Round 18
// 81.489 us; speedup vs baseline: 2.1050x; 1.5473x over previous
//
#include <hip/hip_runtime.h>
#include <hip/hip_bf16.h>

typedef __attribute__((ext_vector_type(8))) short bf16x8;
typedef __attribute__((ext_vector_type(4))) float f32x4;

#define N_TOKENS 16384
#define DIM 4096
#define TOKB 32            // tokens per block
#define BK 128             // K floats per staged tile
#define NIT (DIM / BK)     // 32 iterations
#define NBUF 4
#define BUF_F (TOKB * BK)  // 4096 floats (16 KB) per buffer
#define N_EXP 64

// d_out layout (all float32):
//   [0, 32768)              topk_experts as float  [token][2]
//   [32768, 65536)          combine_weight         [token][2]
//   [65536, 65536+1048576)  scores                 [token][64]
//   [1114112]               load_balance_loss
//   [1114113]               z_loss
#define OFF_W   (N_TOKENS * 2)
#define OFF_S   (N_TOKENS * 4)
#define OFF_LBL (N_TOKENS * 4 + N_TOKENS * N_EXP)
#define OFF_Z   (OFF_LBL + 1)

// ws layout (floats): [0..63] me, [64..127] ce, [128] z,
// [512..) w_hi packed ushort[64*4096] (512 KB), then w_lo packed ushort[64*4096]
#define WS_WHI_F 512
#define WS_WLO_F (512 + (N_EXP * DIM) / 2)

typedef const __attribute__((address_space(1))) void GV;
typedef __attribute__((address_space(3))) void LV;

// ---- cheap truncation split: f = hi + r exactly; lo = trunc(r). ~3 VALU/elem.
__device__ __forceinline__ unsigned int pkhi(float a, float b) {
  return __builtin_amdgcn_perm(__float_as_uint(b), __float_as_uint(a), 0x07060302u);
}
__device__ __forceinline__ float resid(float f) {
  return f - __uint_as_float(__float_as_uint(f) & 0xFFFF0000u);
}
__device__ __forceinline__ void tsplit8(const f32x4 p0, const f32x4 p1,
                                        bf16x8& hi, bf16x8& lo) {
  uint4 H = make_uint4(pkhi(p0[0], p0[1]), pkhi(p0[2], p0[3]),
                       pkhi(p1[0], p1[1]), pkhi(p1[2], p1[3]));
  float r0 = resid(p0[0]), r1 = resid(p0[1]), r2 = resid(p0[2]), r3 = resid(p0[3]);
  float r4 = resid(p1[0]), r5 = resid(p1[1]), r6 = resid(p1[2]), r7 = resid(p1[3]);
  uint4 L = make_uint4(pkhi(r0, r1), pkhi(r2, r3), pkhi(r4, r5), pkhi(r6, r7));
  hi = __builtin_bit_cast(bf16x8, H);
  lo = __builtin_bit_cast(bf16x8, L);
}

// pre-pass: w fp32 -> bf16 hi/lo planes, PRE-PACKED into MFMA fragment order.
// plane layout: [kq(4)][q(2)][it(32)][n(2)][lane(64)*8 ushorts]
//   source (e,k): q=e>>5, n=(e>>4)&1, r15=e&15; it=k>>7, kq=(k>>5)&3,
//   half=(k>>3)&3, j=k&7; lane = half*16 + r15.
__global__ __launch_bounds__(256) void split_w_kernel(
    const float* __restrict__ w,
    unsigned short* __restrict__ whi, unsigned short* __restrict__ wlo)
{
  const int i = blockIdx.x * 256 + threadIdx.x;  // 0 .. 64*4096-1
  const int e = i >> 12, k = i & 4095;
  float f = w[i];
  unsigned short h = __builtin_bit_cast(unsigned short, __float2bfloat16(f));
  float hf = __uint_as_float(((unsigned)h) << 16);
  unsigned short l = __builtin_bit_cast(unsigned short, __float2bfloat16(f - hf));
  const int q = e >> 5, n = (e >> 4) & 1, r15 = e & 15;
  const int it = k >> 7, kq = (k >> 5) & 3, half = (k >> 3) & 3, j = k & 7;
  const int lane = half * 16 + r15;
  const int idx = (((kq * 2 + q) * 32 + it) * 1024) + n * 512 + lane * 8 + j;
  whi[idx] = h;
  wlo[idx] = l;
}

__global__ __launch_bounds__(512, 4) void router_kernel(
    const float* __restrict__ x,
    const unsigned short* __restrict__ whi, const unsigned short* __restrict__ wlo,
    float* __restrict__ out, float* __restrict__ ws)
{
  // 4 linear fp32 x-tile buffers [32][128] (64 KB); reused as logits in epilogue.
  // Content is source-swizzled at 16B granularity: LDS[row][u] = x[row][u ^ (row&7)]
  __shared__ __align__(16) float smem[NBUF * BUF_F];

  const int tid  = threadIdx.x;
  const int lane = tid & 63;
  const int wv   = __builtin_amdgcn_readfirstlane(tid >> 6);  // 0..7, wave-uniform
  const int q    = wv & 1;     // expert half (32 experts)
  const int kq   = wv >> 1;    // k-slice: 0..3 (32 floats each within BK)
  const int half = lane >> 4;  // 0..3
  const int r15  = lane & 15;
  const int tok0 = blockIdx.x * TOKB;

  // staging (identical to r12): wave wv covers rows wv*4..+3 of the [32][128] tile
  const int row0 = wv * 4 + (lane >> 5);
  const int row1 = row0 + 2;
  const int sU   = lane & 31;
  const float* g0 = x + (size_t)(tok0 + row0) * DIM + ((sU ^ (row0 & 7)) << 2);
  const float* g1 = x + (size_t)(tok0 + row1) * DIM + ((sU ^ (row1 & 7)) << 2);
  float* const ldst = smem + wv * 512;  // wave-uniform

#define STAGE(buf, it_) do {                                                  \
    const float* s0_ = g0 + (size_t)(it_) * BK;                               \
    const float* s1_ = g1 + (size_t)(it_) * BK;                               \
    float* d_ = ldst + (buf) * BUF_F;                                         \
    __builtin_amdgcn_global_load_lds((GV*)s0_, (LV*)d_,       16, 0, 0);      \
    __builtin_amdgcn_global_load_lds((GV*)s1_, (LV*)(d_+256), 16, 0, 0);      \
  } while (0)

  // packed w: this wave's contiguous 64 KB region per plane, walked linearly
  const unsigned short* wph = whi + ((kq * 2 + q) << 15);  // *32768 ushorts
  const unsigned short* wpl = wlo + ((kq * 2 + q) << 15);
  const int lo16 = lane * 8;  // lane's 16B slot within each 1KB cell

  f32x4 acc[2][2];
#pragma unroll
  for (int tt = 0; tt < 2; ++tt)
#pragma unroll
    for (int n = 0; n < 2; ++n) acc[tt][n] = (f32x4){0.f, 0.f, 0.f, 0.f};

  // ---- prologue: FIFO = stage0(2), stage1(2) ----
  STAGE(0, 0);
  STAGE(1, 1);

  for (int it = 0; it < NIT; ++it) {
    const int cur = it & 3;
    // 4 coalesced w-loads for this iter (1 KB contiguous per wave each)
    const unsigned short* ph = wph + it * 1024;
    const unsigned short* pl = wpl + it * 1024;
    bf16x8 bh0 = *(const bf16x8*)(ph + lo16);
    bf16x8 bh1 = *(const bf16x8*)(ph + 512 + lo16);
    bf16x8 bl0 = *(const bf16x8*)(pl + lo16);
    bf16x8 bl1 = *(const bf16x8*)(pl + 512 + lo16);
    // stage it+2 (clamped) -- 2 vmem ops
    STAGE((it + 2) & 3, (it + 2 < NIT) ? it + 2 : NIT - 1);

    // retire everything older than this iter's 6 ops + prev stage(it+1):
    // guarantees stage(it) landed; keeps stage(it+1) and this iter's w in flight.
    asm volatile("s_waitcnt vmcnt(8)" ::: "memory");
    __builtin_amdgcn_s_barrier();

    // ---- compute from buf cur: swizzled fp32 reads -> trunc-split -> 12 MFMA ----
    const float* bufp = smem + cur * BUF_F;
#pragma unroll
    for (int tt = 0; tt < 2; ++tt) {
      const int rowA = tt * 16 + r15;
      const int g    = r15 & 7;
      const float* rp = bufp + rowA * BK;
      const int u0 = kq * 8 + ((half * 2) ^ g);
      const int u1 = kq * 8 + ((half * 2 + 1) ^ g);
      f32x4 p0 = *(const f32x4*)(rp + (u0 << 2));
      f32x4 p1 = *(const f32x4*)(rp + (u1 << 2));
      bf16x8 ah, al;
      tsplit8(p0, p1, ah, al);
      acc[tt][0] = __builtin_amdgcn_mfma_f32_16x16x32_bf16(ah, bh0, acc[tt][0], 0, 0, 0);
      acc[tt][0] = __builtin_amdgcn_mfma_f32_16x16x32_bf16(al, bh0, acc[tt][0], 0, 0, 0);
      acc[tt][0] = __builtin_amdgcn_mfma_f32_16x16x32_bf16(ah, bl0, acc[tt][0], 0, 0, 0);
      acc[tt][1] = __builtin_amdgcn_mfma_f32_16x16x32_bf16(ah, bh1, acc[tt][1], 0, 0, 0);
      acc[tt][1] = __builtin_amdgcn_mfma_f32_16x16x32_bf16(al, bh1, acc[tt][1], 0, 0, 0);
      acc[tt][1] = __builtin_amdgcn_mfma_f32_16x16x32_bf16(ah, bl1, acc[tt][1], 0, 0, 0);
    }
  }

  // drain all outstanding gll writes (incl. clamped tail stages) before smem reuse
  asm volatile("s_waitcnt vmcnt(0)" ::: "memory");
  __syncthreads();

  // ---- epilogue: reuse smem as 4 kq-partial logit buffers [32][65] ----
  float* lb = smem;
  {
    float* dst = lb + kq * (TOKB * 65);
#pragma unroll
    for (int tt = 0; tt < 2; ++tt) {
#pragma unroll
      for (int n = 0; n < 2; ++n) {
#pragma unroll
        for (int r = 0; r < 4; ++r) {
          dst[(tt * 16 + half * 4 + r) * 65 + q * 32 + n * 16 + r15] = acc[tt][n][r];
        }
      }
    }
  }
  __syncthreads();

  // combine the four kq partials
  for (int i = tid; i < TOKB * 64; i += 512) {
    const int t = i >> 6, e = i & 63;
    lb[t * 65 + e] += lb[2080 + t * 65 + e] + lb[4160 + t * 65 + e] + lb[6240 + t * 65 + e];
  }
  __syncthreads();

  if (wv == 0 && lane < TOKB) {
    // lane owns one token: full softmax + top-2 + z-loss
    const int token = tok0 + lane;
    float v[64];
#pragma unroll
    for (int e = 0; e < 64; ++e) v[e] = lb[lane * 65 + e];
    float m = v[0];
#pragma unroll
    for (int e = 1; e < 64; ++e) m = fmaxf(m, v[e]);
    float sum = 0.f;
#pragma unroll
    for (int e = 0; e < 64; ++e) { v[e] = expf(v[e] - m); sum += v[e]; }
    const float inv = 1.0f / sum;
    float m1 = -1.f, m2 = -1.f;
    int   i1 = 0,    i2 = 0;
#pragma unroll
    for (int e = 0; e < 64; ++e) {
      float sc = v[e] * inv;
      lb[lane * 65 + e] = sc;
      if (sc > m1)      { m2 = m1; i2 = i1; m1 = sc; i1 = e; }
      else if (sc > m2) { m2 = sc; i2 = e; }
    }
    out[2 * token]         = (float)i1;
    out[2 * token + 1]     = (float)i2;
    out[OFF_W + 2 * token]     = m1;
    out[OFF_W + 2 * token + 1] = m2;

    float lse = m + logf(sum);
    float z = lse * lse;
#pragma unroll
    for (int off = 16; off > 0; off >>= 1) z += __shfl_down(z, off);
    if (lane == 0) atomicAdd(ws + 128, z);
  }
  __syncthreads();

  // coalesced scores store for this block's 32 tokens
  float* outS = out + OFF_S + (size_t)blockIdx.x * TOKB * 64;
  for (int i = tid; i < TOKB * 64; i += 512) {
    outS[i] = lb[(i >> 6) * 65 + (i & 63)];
  }

  // per-expert partial me / ce for this block's tokens (expert = lane)
  if (wv == 0) {
    float sm = 0.f, cn = 0.f;
#pragma unroll
    for (int t = 0; t < TOKB; ++t) {
      float sc = lb[t * 65 + lane];
      sm += sc;
      cn += (sc > 0.f) ? 1.f : 0.f;
    }
    atomicAdd(ws + lane, sm);
    atomicAdd(ws + 64 + lane, cn);
  }
#undef STAGE
}

__global__ void finalize_kernel(const float* __restrict__ ws, float* __restrict__ out) {
  const int l = threadIdx.x;  // 64 threads
  const float invT = 1.0f / (float)N_TOKENS;
  float me = ws[l] * invT;
  float ce = ws[64 + l] * invT;
  float p = me * ce;
#pragma unroll
  for (int off = 32; off > 0; off >>= 1) p += __shfl_down(p, off);
  if (l == 0) {
    out[OFF_LBL] = p * (float)N_EXP;
    out[OFF_Z]   = ws[128] * invT;
  }
}

extern "C" void kernel_launch(void* const* d_in, const int* in_sizes, int n_in,
                              void* d_out, int out_size, void* d_ws, size_t ws_size,
                              hipStream_t stream) {
  const float* x = (const float*)d_in[0];
  const float* w = (const float*)d_in[1];
  float* out = (float*)d_out;
  float* ws  = (float*)d_ws;
  unsigned short* whi = (unsigned short*)(ws + WS_WHI_F);
  unsigned short* wlo = (unsigned short*)(ws + WS_WLO_F);

  (void)hipMemsetAsync(d_ws, 0, 129 * sizeof(float), stream);
  split_w_kernel<<<(N_EXP * DIM) / 256, 256, 0, stream>>>(w, whi, wlo);
  router_kernel<<<N_TOKENS / TOKB, 512, 0, stream>>>(x, whi, wlo, out, ws);
  finalize_kernel<<<1, 64, 0, stream>>>(ws, out);
}